// Round 1
// baseline (226.257 us; speedup 1.0000x reference)
//
#include <hip/hip_runtime.h>
#include <cstddef>
#include <cstdint>

// Accumulator slots (float, in ws[0..256))
enum {
  A_SUM_E = 0, A_SUM_A, A_SUM_I, A_SUM_L, A_MAXQ,
  A_EQ, A_CNT_FREE, A_FREE, A_CNT_FFACE,
  A_SUPX, A_SUPY, A_SUPZ, A_CNT_SD, A_CNT_SR,
  A_LN, A_LMK, A_LMPP, A_LENDM, A_LENDV,
  A_COUNT
};

__device__ __forceinline__ float wave_sum(float v) {
#pragma unroll
  for (int off = 32; off > 0; off >>= 1) v += __shfl_down(v, off, 64);
  return v;
}
__device__ __forceinline__ float wave_max(float v) {
#pragma unroll
  for (int off = 32; off > 0; off >>= 1) v = fmaxf(v, __shfl_down(v, off, 64));
  return v;
}

// Block-level commit of NA per-thread partial accumulators into global acc.
// maxSlot (if >=0) is combined with max (atomicMax on float bits, values >= 0),
// all others with sum (atomicAdd). Block size must be 256 (4 waves).
template <int NA>
__device__ __forceinline__ void commit_acc(float* gacc, float (&l)[NA], int maxSlot) {
  __shared__ float s[4][NA];
  const int wid = threadIdx.x >> 6, lane = threadIdx.x & 63;
#pragma unroll
  for (int i = 0; i < NA; i++) {
    float r = (i == maxSlot) ? wave_max(l[i]) : wave_sum(l[i]);
    if (lane == 0) s[wid][i] = r;
  }
  __syncthreads();
  if ((int)threadIdx.x < NA) {
    const int i = threadIdx.x;
    if (i == maxSlot) {
      float m = fmaxf(fmaxf(s[0][i], s[1][i]), fmaxf(s[2][i], s[3][i]));
      atomicMax((unsigned int*)&gacc[i], __float_as_uint(m));
    } else {
      float v = (s[0][i] + s[1][i]) + (s[2][i] + s[3][i]);
      atomicAdd(&gacc[i], v);
    }
  }
}

// Pass 1: node-indexed terms + ff scatter + element ref reductions (N and E
// iterated by the same grid-stride loop).
__global__ __launch_bounds__(256) void k_pass1(
    const float* __restrict__ pred, const float* __restrict__ F_ext,
    const float* __restrict__ bc_disp, const float* __restrict__ bc_rot,
    const float* __restrict__ face_mask,
    const int* __restrict__ f_eid, const int* __restrict__ f_isA,
    const float* __restrict__ pE, const float* __restrict__ pA,
    const float* __restrict__ pI, const float* __restrict__ pL,
    const float* __restrict__ eload,
    float* __restrict__ ffA, float* __restrict__ ffB,
    float* __restrict__ dispc, float* __restrict__ qmag,
    float* __restrict__ gacc, int N, int E) {
  float l[A_COUNT];
#pragma unroll
  for (int i = 0; i < A_COUNT; i++) l[i] = 0.f;

  const int total = (N > E) ? N : E;
  const int stride = gridDim.x * blockDim.x;
  for (int i = blockIdx.x * blockDim.x + threadIdx.x; i < total; i += stride) {
    if (i < N) {
      const float* row = pred + (size_t)i * 15u;
      const float d0 = row[0], d1 = row[1], d2 = row[2];
      float ff[12];
#pragma unroll
      for (int j = 0; j < 12; j++) ff[j] = row[3 + j];
      const float s0 = (ff[0] + ff[3]) + (ff[6] + ff[9]);
      const float s1 = (ff[1] + ff[4]) + (ff[7] + ff[10]);
      const float s2 = (ff[2] + ff[5]) + (ff[8] + ff[11]);
      const size_t i3 = (size_t)i * 3u;
      const float r0 = s0 - F_ext[i3], r1 = s1 - F_ext[i3 + 1], r2 = s2 - F_ext[i3 + 2];
      const float bd = bc_disp[i], br = bc_rot[i];
      if (bd < 0.5f) { l[A_EQ] += r0 * r0 + r1 * r1 + r2 * r2; l[A_CNT_FREE] += 1.f; }
      if (bd > 0.5f) { l[A_SUPX] += d0 * d0; l[A_SUPY] += d1 * d1; l[A_CNT_SD] += 1.f; }
      if (br > 0.5f) { l[A_SUPZ] += d2 * d2; l[A_CNT_SR] += 1.f; }
      const size_t i4 = (size_t)i * 4u;
#pragma unroll
      for (int f = 0; f < 4; f++) {
        const float fm = face_mask[i4 + f];
        const float x = ff[3 * f], y = ff[3 * f + 1], z = ff[3 * f + 2];
        if (fm < 0.5f) {
          l[A_FREE] += x * x + y * y + z * z;
          l[A_CNT_FFACE] += 1.f;
        } else {
          const int eid = f_eid[i4 + f];
          const int isA = f_isA[i4 + f];
          if (eid >= 0 && eid < E && (isA == 0 || isA == 1)) {
            float* dst = (isA == 1) ? ffA : ffB;
            const size_t e3 = (size_t)eid * 3u;
            dst[e3] = x; dst[e3 + 1] = y; dst[e3 + 2] = z;
          }
        }
      }
      if (dispc) { dispc[(size_t)i * 2u] = d0; dispc[(size_t)i * 2u + 1] = d1; }
    }
    if (i < E) {
      l[A_SUM_E] += pE[i]; l[A_SUM_A] += pA[i]; l[A_SUM_I] += pI[i]; l[A_SUM_L] += pL[i];
      const size_t i3 = (size_t)i * 3u;
      const float q0 = eload[i3], q1 = eload[i3 + 1], q2 = eload[i3 + 2];
      const float q = sqrtf(q0 * q0 + q1 * q1 + q2 * q2);
      if (qmag) qmag[i] = q;
      l[A_MAXQ] = fmaxf(l[A_MAXQ], q);
    }
  }
  commit_acc<A_COUNT>(gacc, l, A_MAXQ);
}

// Pass 2: element loss numerators (L_N, L_Mk, L_Mpp, L_end).
__global__ __launch_bounds__(256) void k_pass2(
    const int* __restrict__ conn, const float* __restrict__ dirs,
    const float* __restrict__ pE, const float* __restrict__ pA,
    const float* __restrict__ pI, const float* __restrict__ pL,
    const float* __restrict__ eload, const float* __restrict__ cw,
    const float* __restrict__ cMc,
    const float* __restrict__ ffA, const float* __restrict__ ffB,
    const float* __restrict__ dispc, const float* __restrict__ pred,
    const float* __restrict__ qmag,
    float* __restrict__ gacc, int N, int E) {
  float l[5];  // LN, LMK, LMPP, LENDM, LENDV
#pragma unroll
  for (int i = 0; i < 5; i++) l[i] = 0.f;

  const int stride = gridDim.x * blockDim.x;
  for (int i = blockIdx.x * blockDim.x + threadIdx.x; i < E; i += stride) {
    const size_t i2 = (size_t)i * 2u, i3 = (size_t)i * 3u;
    const int nA = conn[i2], nB = conn[i2 + 1];
    float dAx, dAy, dBx, dBy;
    if (dispc) {
      dAx = dispc[(size_t)nA * 2u]; dAy = dispc[(size_t)nA * 2u + 1];
      dBx = dispc[(size_t)nB * 2u]; dBy = dispc[(size_t)nB * 2u + 1];
    } else {
      dAx = pred[(size_t)nA * 15u]; dAy = pred[(size_t)nA * 15u + 1];
      dBx = pred[(size_t)nB * 15u]; dBy = pred[(size_t)nB * 15u + 1];
    }
    const float c = dirs[i3], s = dirs[i3 + 2];
    const float fax = ffA[i3], fay = ffA[i3 + 1], faz = ffA[i3 + 2];
    const float fbx = ffB[i3], fby = ffB[i3 + 1], fbz = ffB[i3 + 2];
    const float fA0 = fax * c + fay * s, fA1 = -fax * s + fay * c, fA2 = faz;
    const float fB0 = fbx * c + fby * s, fB1 = -fbx * s + fby * c, fB2 = fbz;
    const float dA0 = dAx * c + dAy * s, dB0 = dBx * c + dBy * s;
    const float L = pL[i];
    const float invL = 1.0f / L, invL2 = invL * invL;
    const float Nax = pE[i] * pA[i] * (dB0 - dA0) * invL;
    {
      const float t0 = fA0 + Nax, t1 = fB0 - Nax;
      l[0] += t0 * t0 + t1 * t1;
    }
    const float EI = pE[i] * pI[i];
    const size_t i6 = (size_t)i * 6u, i4 = (size_t)i * 4u;
    const float c2 = cw[i6 + 2], c3 = cw[i6 + 3], c4 = cw[i6 + 4], c5 = cw[i6 + 5];
    const float m0 = cMc[i4], m1 = cMc[i4 + 1], m2 = cMc[i4 + 2], m3 = cMc[i4 + 3];
    float q;
    if (qmag) {
      q = qmag[i];
    } else {
      const float q0 = eload[i3], q1 = eload[i3 + 1], q2 = eload[i3 + 2];
      q = sqrtf(q0 * q0 + q1 * q1 + q2 * q2);
    }
#pragma unroll
    for (int k = 0; k < 5; k++) {
      const float xi = 0.25f * (float)k;
      const float d2w = (2.f * c2 + xi * (6.f * c3 + xi * (12.f * c4 + xi * (20.f * c5)))) * invL2;
      const float M = m0 + xi * (m1 + xi * (m2 + xi * m3));
      const float t = M - EI * d2w;
      l[1] += t * t;
      if (k >= 1 && k <= 3) {
        const float d2M = (2.f * m2 + 6.f * xi * m3) * invL2;
        const float u = d2M + q;
        l[2] += u * u;
      }
    }
    const float MA = m0, MB = ((m0 + m1) + (m2 + m3));
    const float VA = m1 * invL, VB = (m1 + 2.f * m2 + 3.f * m3) * invL;
    const float e0 = fA2 + MA, e1 = fB2 - MB;
    l[3] += e0 * e0 + e1 * e1;
    const float e2 = fA1 + VA, e3 = fB1 - VB;
    l[4] += e2 * e2 + e3 * e3;
  }
  commit_acc<5>(gacc + A_LN, l, -1);  // A_LN..A_LENDV are contiguous
}

// Finisher: combine accumulators with reference scalars.
__global__ void k_finish(const float* __restrict__ acc, float* __restrict__ out,
                         float fE) {
  if (threadIdx.x == 0 && blockIdx.x == 0) {
    const float E_ref = acc[A_SUM_E] / fE;
    const float A_ref = acc[A_SUM_A] / fE;
    const float I_ref = acc[A_SUM_I] / fE;
    const float L_ref = acc[A_SUM_L] / fE;
    float q0 = acc[A_MAXQ];  // stored as float bits via atomicMax-on-uint
    if (q0 < 1e-10f) q0 = 1.0f;
    const float N_ref = fmaxf(E_ref * A_ref * 0.001f / L_ref, 1e-6f);
    const float M_ref = fmaxf(E_ref * I_ref * 0.001f / (L_ref * L_ref), 1e-6f);
    const float V_ref = fmaxf(M_ref / L_ref, 1e-6f);
    const float q_ref = fmaxf(q0, 1e-6f);
    const float F_ref = fmaxf(q0 * L_ref, 1e-6f);

    const float L_eq = acc[A_EQ] / (F_ref * F_ref) / fmaxf(acc[A_CNT_FREE], 1.f);
    const float L_free = acc[A_FREE] / (F_ref * F_ref) / fmaxf(acc[A_CNT_FFACE] * 3.f, 1.f);
    const float cd = fmaxf(acc[A_CNT_SD], 1.f), cr = fmaxf(acc[A_CNT_SR], 1.f);
    const float L_sup = acc[A_SUPX] / cd + acc[A_SUPY] / cd + acc[A_SUPZ] / cr;
    const float L_N = acc[A_LN] / (N_ref * N_ref) / fE;
    const float L_Mk = acc[A_LMK] / (M_ref * M_ref) / (fE * 5.f);
    const float L_Mpp = acc[A_LMPP] / (q_ref * q_ref) / (fE * 3.f);
    const float L_end = acc[A_LENDM] / (M_ref * M_ref) / fE +
                        acc[A_LENDV] / (V_ref * V_ref) / fE;
    out[0] = ((L_eq + L_free) + (L_sup + L_N)) + ((L_Mk + L_Mpp) + L_end);
  }
}

extern "C" void kernel_launch(void* const* d_in, const int* in_sizes, int n_in,
                              void* d_out, int out_size, void* d_ws, size_t ws_size,
                              hipStream_t stream) {
  const float* pred = (const float*)d_in[0];
  const float* F_ext = (const float*)d_in[1];
  const float* bc_disp = (const float*)d_in[2];
  const float* bc_rot = (const float*)d_in[3];
  const float* face_mask = (const float*)d_in[4];
  const float* dirs = (const float*)d_in[5];
  const float* pE = (const float*)d_in[6];
  const float* pA = (const float*)d_in[7];
  const float* pI = (const float*)d_in[8];
  const float* pL = (const float*)d_in[9];
  const float* eload = (const float*)d_in[10];
  const float* cw = (const float*)d_in[11];
  const float* cMc = (const float*)d_in[12];
  const int* conn = (const int*)d_in[13];
  const int* f_eid = (const int*)d_in[14];
  const int* f_isA = (const int*)d_in[15];

  const int N = in_sizes[1] / 3;  // F_ext is (N,3)
  const int E = in_sizes[6];      // prop_E is (E,)

  char* ws = (char*)d_ws;
  float* gacc = (float*)ws;
  size_t off = 256;
  float* ffA = (float*)(ws + off); off += (size_t)E * 3u * sizeof(float);
  float* ffB = (float*)(ws + off); off += (size_t)E * 3u * sizeof(float);
  float* dispc = nullptr;
  float* qmag = nullptr;
  if (ws_size >= off + (size_t)N * 2u * sizeof(float)) {
    dispc = (float*)(ws + off); off += (size_t)N * 2u * sizeof(float);
  }
  if (ws_size >= off + (size_t)E * sizeof(float)) {
    qmag = (float*)(ws + off); off += (size_t)E * sizeof(float);
  }

  hipMemsetAsync(gacc, 0, 256, stream);

  const int BLK = 256;
  const int GRID = 4096;  // grid-stride
  k_pass1<<<GRID, BLK, 0, stream>>>(pred, F_ext, bc_disp, bc_rot, face_mask,
                                    f_eid, f_isA, pE, pA, pI, pL, eload,
                                    ffA, ffB, dispc, qmag, gacc, N, E);
  k_pass2<<<GRID, BLK, 0, stream>>>(conn, dirs, pE, pA, pI, pL, eload, cw, cMc,
                                    ffA, ffB, dispc, pred, qmag, gacc, N, E);
  k_finish<<<1, 64, 0, stream>>>(gacc, (float*)d_out, (float)E);
}

// Round 2
// 195.268 us; speedup vs baseline: 1.1587x; 1.1587x over previous
//
#include <hip/hip_runtime.h>
#include <cstddef>
#include <cstdint>

// Global accumulator slots (float, in ws[0..256)).
// Grouped so each kernel commits a contiguous sub-range.
enum {
  // node kernel: 0..8
  A_EQ = 0, A_CNT_FREE, A_FREE, A_CNT_FFACE,
  A_SUPX, A_SUPY, A_SUPZ, A_CNT_SD, A_CNT_SR,
  // element kernel 1: 9..15  (MAXQ last: max-combined)
  A_SUM_E, A_SUM_A, A_SUM_I, A_SUM_L, A_LMK, A_LMPP, A_MAXQ,
  // pass 2: 16..18
  A_LN, A_LENDM, A_LENDV,
  A_COUNT
};

__device__ __forceinline__ float wave_sum(float v) {
#pragma unroll
  for (int off = 32; off > 0; off >>= 1) v += __shfl_down(v, off, 64);
  return v;
}
__device__ __forceinline__ float wave_max(float v) {
#pragma unroll
  for (int off = 32; off > 0; off >>= 1) v = fmaxf(v, __shfl_down(v, off, 64));
  return v;
}

// Block-level commit of NA per-thread partial accumulators into gacc[0..NA).
// maxSlot (if >=0) combined via atomicMax on float bits (values >= 0),
// others via atomicAdd. Block must be 256 threads (4 waves).
template <int NA>
__device__ __forceinline__ void commit_acc(float* gacc, float (&l)[NA], int maxSlot) {
  __shared__ float s[4][NA];
  const int wid = threadIdx.x >> 6, lane = threadIdx.x & 63;
#pragma unroll
  for (int i = 0; i < NA; i++) {
    float r = (i == maxSlot) ? wave_max(l[i]) : wave_sum(l[i]);
    if (lane == 0) s[wid][i] = r;
  }
  __syncthreads();
  if ((int)threadIdx.x < NA) {
    const int i = threadIdx.x;
    if (i == maxSlot) {
      float m = fmaxf(fmaxf(s[0][i], s[1][i]), fmaxf(s[2][i], s[3][i]));
      atomicMax((unsigned int*)&gacc[i], __float_as_uint(m));
    } else {
      float v = (s[0][i] + s[1][i]) + (s[2][i] + s[3][i]);
      atomicAdd(&gacc[i], v);
    }
  }
}

// ---------------- Node kernel: L_eq, L_free, L_sup + ff scatter + dispc ----
__global__ __launch_bounds__(256) void k_node(
    const float* __restrict__ pred, const float* __restrict__ F_ext,
    const float* __restrict__ bc_disp, const float* __restrict__ bc_rot,
    const float* __restrict__ face_mask,
    const int* __restrict__ f_eid, const int* __restrict__ f_isA,
    float* __restrict__ ffA, float* __restrict__ ffB,
    float* __restrict__ dispc,
    float* __restrict__ gacc, int N, int E) {
  float l[9];
#pragma unroll
  for (int i = 0; i < 9; i++) l[i] = 0.f;

  const float4* pred4 = (const float4*)pred;
  const float4* fext4 = (const float4*)F_ext;
  const float4* bd4p = (const float4*)bc_disp;
  const float4* br4p = (const float4*)bc_rot;
  const float4* fm4 = (const float4*)face_mask;
  const int4* fid4 = (const int4*)f_eid;
  const int4* fia4 = (const int4*)f_isA;
  float4* dispc4 = (float4*)dispc;

  const int nG = (N + 3) >> 2;
  const int stride = gridDim.x * blockDim.x;
  for (int g = blockIdx.x * blockDim.x + threadIdx.x; g < nG; g += stride) {
    const int base = g << 2;
    if (base + 3 < N) {
      float4 p[15];
      const float4* pr = pred4 + (size_t)g * 15u;
#pragma unroll
      for (int j = 0; j < 15; j++) p[j] = pr[j];
      float4 fe[3];
#pragma unroll
      for (int j = 0; j < 3; j++) fe[j] = fext4[(size_t)g * 3u + j];
      const float4 bd = bd4p[g];
      const float4 br = br4p[g];
      float4 fm[4]; int4 fid[4]; int4 fia[4];
#pragma unroll
      for (int r = 0; r < 4; r++) {
        fm[r] = fm4[(size_t)base + r];
        fid[r] = fid4[(size_t)base + r];
        fia[r] = fia4[(size_t)base + r];
      }
      const float* pf = (const float*)p;
      const float* fef = (const float*)fe;
      const float* bdf = (const float*)&bd;
      const float* brf = (const float*)&br;
      float dout[8];
#pragma unroll
      for (int r = 0; r < 4; r++) {
        const float* row = pf + r * 15;
        const float d0 = row[0], d1 = row[1], d2 = row[2];
        dout[r * 2] = d0; dout[r * 2 + 1] = d1;
        const float s0 = (row[3] + row[6]) + (row[9] + row[12]);
        const float s1 = (row[4] + row[7]) + (row[10] + row[13]);
        const float s2 = (row[5] + row[8]) + (row[11] + row[14]);
        const float r0 = s0 - fef[r * 3], r1 = s1 - fef[r * 3 + 1], r2 = s2 - fef[r * 3 + 2];
        const float bdv = bdf[r], brv = brf[r];
        if (bdv < 0.5f) { l[0] += r0 * r0 + r1 * r1 + r2 * r2; l[1] += 1.f; }
        if (bdv > 0.5f) { l[4] += d0 * d0; l[5] += d1 * d1; l[7] += 1.f; }
        if (brv > 0.5f) { l[6] += d2 * d2; l[8] += 1.f; }
        const float* fmr = (const float*)&fm[r];
        const int* fidr = (const int*)&fid[r];
        const int* fiar = (const int*)&fia[r];
#pragma unroll
        for (int f = 0; f < 4; f++) {
          const float x = row[3 + 3 * f], y = row[4 + 3 * f], z = row[5 + 3 * f];
          if (fmr[f] < 0.5f) {
            l[2] += x * x + y * y + z * z;
            l[3] += 1.f;
          } else {
            const int eid = fidr[f];
            const int isA = fiar[f];
            if (eid >= 0 && eid < E && (isA == 0 || isA == 1)) {
              float* dst = (isA == 1) ? ffA : ffB;
              const size_t e3 = (size_t)eid * 3u;
              dst[e3] = x; dst[e3 + 1] = y; dst[e3 + 2] = z;
            }
          }
        }
      }
      if (dispc) {
        dispc4[(size_t)g * 2u] = make_float4(dout[0], dout[1], dout[2], dout[3]);
        dispc4[(size_t)g * 2u + 1] = make_float4(dout[4], dout[5], dout[6], dout[7]);
      }
    } else {
      // scalar tail
      for (int r = 0; r < 4; r++) {
        const int i = base + r;
        if (i >= N) break;
        const float* row = pred + (size_t)i * 15u;
        const float d0 = row[0], d1 = row[1], d2 = row[2];
        const float s0 = (row[3] + row[6]) + (row[9] + row[12]);
        const float s1 = (row[4] + row[7]) + (row[10] + row[13]);
        const float s2 = (row[5] + row[8]) + (row[11] + row[14]);
        const size_t i3 = (size_t)i * 3u;
        const float r0 = s0 - F_ext[i3], r1 = s1 - F_ext[i3 + 1], r2 = s2 - F_ext[i3 + 2];
        const float bdv = bc_disp[i], brv = bc_rot[i];
        if (bdv < 0.5f) { l[0] += r0 * r0 + r1 * r1 + r2 * r2; l[1] += 1.f; }
        if (bdv > 0.5f) { l[4] += d0 * d0; l[5] += d1 * d1; l[7] += 1.f; }
        if (brv > 0.5f) { l[6] += d2 * d2; l[8] += 1.f; }
        const size_t i4 = (size_t)i * 4u;
        for (int f = 0; f < 4; f++) {
          const float x = row[3 + 3 * f], y = row[4 + 3 * f], z = row[5 + 3 * f];
          if (face_mask[i4 + f] < 0.5f) {
            l[2] += x * x + y * y + z * z;
            l[3] += 1.f;
          } else {
            const int eid = f_eid[i4 + f];
            const int isA = f_isA[i4 + f];
            if (eid >= 0 && eid < E && (isA == 0 || isA == 1)) {
              float* dst = (isA == 1) ? ffA : ffB;
              const size_t e3 = (size_t)eid * 3u;
              dst[e3] = x; dst[e3 + 1] = y; dst[e3 + 2] = z;
            }
          }
        }
        if (dispc) { dispc[(size_t)i * 2u] = d0; dispc[(size_t)i * 2u + 1] = d1; }
      }
    }
  }
  commit_acc<9>(gacc + A_EQ, l, -1);
}

// -------- Element kernel 1: ref sums + max|q| + L_Mk + L_Mpp (element-local)
__global__ __launch_bounds__(256) void k_elem1(
    const float* __restrict__ pE, const float* __restrict__ pA,
    const float* __restrict__ pI, const float* __restrict__ pL,
    const float* __restrict__ eload, const float* __restrict__ cw,
    const float* __restrict__ cMc,
    float* __restrict__ gacc, int E) {
  float l[7];  // SUM_E, SUM_A, SUM_I, SUM_L, LMK, LMPP, MAXQ
#pragma unroll
  for (int i = 0; i < 7; i++) l[i] = 0.f;

  const float4* pE4 = (const float4*)pE;
  const float4* pA4 = (const float4*)pA;
  const float4* pI4 = (const float4*)pI;
  const float4* pL4 = (const float4*)pL;
  const float4* el4 = (const float4*)eload;
  const float4* cw4 = (const float4*)cw;
  const float4* cM4 = (const float4*)cMc;

  const int nG = (E + 3) >> 2;
  const int stride = gridDim.x * blockDim.x;
  for (int g = blockIdx.x * blockDim.x + threadIdx.x; g < nG; g += stride) {
    const int base = g << 2;
    if (base + 3 < E) {
      const float4 e4 = pE4[g], a4 = pA4[g], i4v = pI4[g], L4 = pL4[g];
      float4 ql[3];
#pragma unroll
      for (int j = 0; j < 3; j++) ql[j] = el4[(size_t)g * 3u + j];
      float4 cwv[6];
#pragma unroll
      for (int j = 0; j < 6; j++) cwv[j] = cw4[(size_t)g * 6u + j];
      float4 cmv[4];
#pragma unroll
      for (int j = 0; j < 4; j++) cmv[j] = cM4[(size_t)g * 4u + j];
      l[0] += (e4.x + e4.y) + (e4.z + e4.w);
      l[1] += (a4.x + a4.y) + (a4.z + a4.w);
      l[2] += (i4v.x + i4v.y) + (i4v.z + i4v.w);
      l[3] += (L4.x + L4.y) + (L4.z + L4.w);
      const float* ef = (const float*)&e4;
      const float* iv = (const float*)&i4v;
      const float* Lf = (const float*)&L4;
      const float* qf = (const float*)ql;
      const float* cwf = (const float*)cwv;
      const float* cmf = (const float*)cmv;
#pragma unroll
      for (int r = 0; r < 4; r++) {
        const float q0 = qf[r * 3], q1 = qf[r * 3 + 1], q2 = qf[r * 3 + 2];
        const float q = sqrtf(q0 * q0 + q1 * q1 + q2 * q2);
        l[6] = fmaxf(l[6], q);
        const float invL = 1.0f / Lf[r];
        const float invL2 = invL * invL;
        const float EI = ef[r] * iv[r];
        const float c2 = cwf[r * 6 + 2], c3 = cwf[r * 6 + 3];
        const float c4 = cwf[r * 6 + 4], c5 = cwf[r * 6 + 5];
        const float m0 = cmf[r * 4], m1 = cmf[r * 4 + 1];
        const float m2 = cmf[r * 4 + 2], m3 = cmf[r * 4 + 3];
#pragma unroll
        for (int k = 0; k < 5; k++) {
          const float xi = 0.25f * (float)k;
          const float d2w = (2.f * c2 + xi * (6.f * c3 + xi * (12.f * c4 + xi * (20.f * c5)))) * invL2;
          const float M = m0 + xi * (m1 + xi * (m2 + xi * m3));
          const float t = M - EI * d2w;
          l[4] += t * t;
          if (k >= 1 && k <= 3) {
            const float d2M = (2.f * m2 + 6.f * xi * m3) * invL2;
            const float u = d2M + q;
            l[5] += u * u;
          }
        }
      }
    } else {
      for (int r = 0; r < 4; r++) {
        const int i = base + r;
        if (i >= E) break;
        l[0] += pE[i]; l[1] += pA[i]; l[2] += pI[i]; l[3] += pL[i];
        const size_t i3 = (size_t)i * 3u;
        const float q0 = eload[i3], q1 = eload[i3 + 1], q2 = eload[i3 + 2];
        const float q = sqrtf(q0 * q0 + q1 * q1 + q2 * q2);
        l[6] = fmaxf(l[6], q);
        const float invL = 1.0f / pL[i];
        const float invL2 = invL * invL;
        const float EI = pE[i] * pI[i];
        const size_t i6 = (size_t)i * 6u, i4 = (size_t)i * 4u;
        const float c2 = cw[i6 + 2], c3 = cw[i6 + 3], c4 = cw[i6 + 4], c5 = cw[i6 + 5];
        const float m0 = cMc[i4], m1 = cMc[i4 + 1], m2 = cMc[i4 + 2], m3 = cMc[i4 + 3];
        for (int k = 0; k < 5; k++) {
          const float xi = 0.25f * (float)k;
          const float d2w = (2.f * c2 + xi * (6.f * c3 + xi * (12.f * c4 + xi * (20.f * c5)))) * invL2;
          const float M = m0 + xi * (m1 + xi * (m2 + xi * m3));
          const float t = M - EI * d2w;
          l[4] += t * t;
          if (k >= 1 && k <= 3) {
            const float d2M = (2.f * m2 + 6.f * xi * m3) * invL2;
            const float u = d2M + q;
            l[5] += u * u;
          }
        }
      }
    }
  }
  commit_acc<7>(gacc + A_SUM_E, l, 6);
}

// ---------------- Pass 2: L_N + L_end (needs scattered ffA/ffB + disp) -----
__global__ __launch_bounds__(256) void k_pass2(
    const int* __restrict__ conn, const float* __restrict__ dirs,
    const float* __restrict__ pE, const float* __restrict__ pA,
    const float* __restrict__ pL, const float* __restrict__ cMc,
    const float* __restrict__ ffA, const float* __restrict__ ffB,
    const float* __restrict__ dispc, const float* __restrict__ pred,
    float* __restrict__ gacc, int N, int E) {
  float l[3];  // LN, LENDM, LENDV
#pragma unroll
  for (int i = 0; i < 3; i++) l[i] = 0.f;

  const int4* conn4 = (const int4*)conn;
  const float4* dir4 = (const float4*)dirs;
  const float4* pE4 = (const float4*)pE;
  const float4* pA4 = (const float4*)pA;
  const float4* pL4 = (const float4*)pL;
  const float4* cM4 = (const float4*)cMc;
  const float4* fA4 = (const float4*)ffA;
  const float4* fB4 = (const float4*)ffB;
  const float2* dsp2 = (const float2*)dispc;

  const int nG = (E + 3) >> 2;
  const int stride = gridDim.x * blockDim.x;
  for (int g = blockIdx.x * blockDim.x + threadIdx.x; g < nG; g += stride) {
    const int base = g << 2;
    if (base + 3 < E) {
      const int4 c01 = conn4[(size_t)g * 2u];
      const int4 c23 = conn4[(size_t)g * 2u + 1];
      const int nAs[4] = {c01.x, c01.z, c23.x, c23.z};
      const int nBs[4] = {c01.y, c01.w, c23.y, c23.w};
      float4 dv[3], fa[3], fb[3];
#pragma unroll
      for (int j = 0; j < 3; j++) {
        dv[j] = dir4[(size_t)g * 3u + j];
        fa[j] = fA4[(size_t)g * 3u + j];
        fb[j] = fB4[(size_t)g * 3u + j];
      }
      const float4 e4 = pE4[g], a4 = pA4[g], L4 = pL4[g];
      float4 cmv[4];
#pragma unroll
      for (int j = 0; j < 4; j++) cmv[j] = cM4[(size_t)g * 4u + j];
      const float* df = (const float*)dv;
      const float* faf = (const float*)fa;
      const float* fbf = (const float*)fb;
      const float* ef = (const float*)&e4;
      const float* af = (const float*)&a4;
      const float* Lf = (const float*)&L4;
      const float* cmf = (const float*)cmv;
#pragma unroll
      for (int r = 0; r < 4; r++) {
        float dAx, dAy, dBx, dBy;
        if (dispc) {
          const float2 dA = dsp2[nAs[r]];
          const float2 dB = dsp2[nBs[r]];
          dAx = dA.x; dAy = dA.y; dBx = dB.x; dBy = dB.y;
        } else {
          dAx = pred[(size_t)nAs[r] * 15u]; dAy = pred[(size_t)nAs[r] * 15u + 1];
          dBx = pred[(size_t)nBs[r] * 15u]; dBy = pred[(size_t)nBs[r] * 15u + 1];
        }
        const float c = df[r * 3], s = df[r * 3 + 2];
        const float fax = faf[r * 3], fay = faf[r * 3 + 1], faz = faf[r * 3 + 2];
        const float fbx = fbf[r * 3], fby = fbf[r * 3 + 1], fbz = fbf[r * 3 + 2];
        const float fA0 = fax * c + fay * s, fA1 = -fax * s + fay * c;
        const float fB0 = fbx * c + fby * s, fB1 = -fbx * s + fby * c;
        const float dA0 = dAx * c + dAy * s, dB0 = dBx * c + dBy * s;
        const float invL = 1.0f / Lf[r];
        const float Nax = ef[r] * af[r] * (dB0 - dA0) * invL;
        const float t0 = fA0 + Nax, t1 = fB0 - Nax;
        l[0] += t0 * t0 + t1 * t1;
        const float m0 = cmf[r * 4], m1 = cmf[r * 4 + 1];
        const float m2 = cmf[r * 4 + 2], m3 = cmf[r * 4 + 3];
        const float MA = m0, MB = (m0 + m1) + (m2 + m3);
        const float VA = m1 * invL, VB = (m1 + 2.f * m2 + 3.f * m3) * invL;
        const float e0 = faz + MA, e1 = fbz - MB;
        l[1] += e0 * e0 + e1 * e1;
        const float e2 = fA1 + VA, e3 = fB1 - VB;
        l[2] += e2 * e2 + e3 * e3;
      }
    } else {
      for (int r = 0; r < 4; r++) {
        const int i = base + r;
        if (i >= E) break;
        const size_t i2 = (size_t)i * 2u, i3 = (size_t)i * 3u, i4 = (size_t)i * 4u;
        const int nA = conn[i2], nB = conn[i2 + 1];
        float dAx, dAy, dBx, dBy;
        if (dispc) {
          dAx = dispc[(size_t)nA * 2u]; dAy = dispc[(size_t)nA * 2u + 1];
          dBx = dispc[(size_t)nB * 2u]; dBy = dispc[(size_t)nB * 2u + 1];
        } else {
          dAx = pred[(size_t)nA * 15u]; dAy = pred[(size_t)nA * 15u + 1];
          dBx = pred[(size_t)nB * 15u]; dBy = pred[(size_t)nB * 15u + 1];
        }
        const float c = dirs[i3], s = dirs[i3 + 2];
        const float fax = ffA[i3], fay = ffA[i3 + 1], faz = ffA[i3 + 2];
        const float fbx = ffB[i3], fby = ffB[i3 + 1], fbz = ffB[i3 + 2];
        const float fA0 = fax * c + fay * s, fA1 = -fax * s + fay * c;
        const float fB0 = fbx * c + fby * s, fB1 = -fbx * s + fby * c;
        const float dA0 = dAx * c + dAy * s, dB0 = dBx * c + dBy * s;
        const float invL = 1.0f / pL[i];
        const float Nax = pE[i] * pA[i] * (dB0 - dA0) * invL;
        const float t0 = fA0 + Nax, t1 = fB0 - Nax;
        l[0] += t0 * t0 + t1 * t1;
        const float m0 = cMc[i4], m1 = cMc[i4 + 1], m2 = cMc[i4 + 2], m3 = cMc[i4 + 3];
        const float MA = m0, MB = (m0 + m1) + (m2 + m3);
        const float VA = m1 * invL, VB = (m1 + 2.f * m2 + 3.f * m3) * invL;
        const float e0 = faz + MA, e1 = fbz - MB;
        l[1] += e0 * e0 + e1 * e1;
        const float e2 = fA1 + VA, e3 = fB1 - VB;
        l[2] += e2 * e2 + e3 * e3;
      }
    }
  }
  commit_acc<3>(gacc + A_LN, l, -1);
}

// ---------------- Finisher ----------------
__global__ void k_finish(const float* __restrict__ acc, float* __restrict__ out,
                         float fE) {
  if (threadIdx.x == 0 && blockIdx.x == 0) {
    const float E_ref = acc[A_SUM_E] / fE;
    const float A_ref = acc[A_SUM_A] / fE;
    const float I_ref = acc[A_SUM_I] / fE;
    const float L_ref = acc[A_SUM_L] / fE;
    float q0 = acc[A_MAXQ];
    if (q0 < 1e-10f) q0 = 1.0f;
    const float N_ref = fmaxf(E_ref * A_ref * 0.001f / L_ref, 1e-6f);
    const float M_ref = fmaxf(E_ref * I_ref * 0.001f / (L_ref * L_ref), 1e-6f);
    const float V_ref = fmaxf(M_ref / L_ref, 1e-6f);
    const float q_ref = fmaxf(q0, 1e-6f);
    const float F_ref = fmaxf(q0 * L_ref, 1e-6f);

    const float L_eq = acc[A_EQ] / (F_ref * F_ref) / fmaxf(acc[A_CNT_FREE], 1.f);
    const float L_free = acc[A_FREE] / (F_ref * F_ref) / fmaxf(acc[A_CNT_FFACE] * 3.f, 1.f);
    const float cd = fmaxf(acc[A_CNT_SD], 1.f), cr = fmaxf(acc[A_CNT_SR], 1.f);
    const float L_sup = acc[A_SUPX] / cd + acc[A_SUPY] / cd + acc[A_SUPZ] / cr;
    const float L_N = acc[A_LN] / (N_ref * N_ref) / fE;
    const float L_Mk = acc[A_LMK] / (M_ref * M_ref) / (fE * 5.f);
    const float L_Mpp = acc[A_LMPP] / (q_ref * q_ref) / (fE * 3.f);
    const float L_end = acc[A_LENDM] / (M_ref * M_ref) / fE +
                        acc[A_LENDV] / (V_ref * V_ref) / fE;
    out[0] = ((L_eq + L_free) + (L_sup + L_N)) + ((L_Mk + L_Mpp) + L_end);
  }
}

extern "C" void kernel_launch(void* const* d_in, const int* in_sizes, int n_in,
                              void* d_out, int out_size, void* d_ws, size_t ws_size,
                              hipStream_t stream) {
  const float* pred = (const float*)d_in[0];
  const float* F_ext = (const float*)d_in[1];
  const float* bc_disp = (const float*)d_in[2];
  const float* bc_rot = (const float*)d_in[3];
  const float* face_mask = (const float*)d_in[4];
  const float* dirs = (const float*)d_in[5];
  const float* pE = (const float*)d_in[6];
  const float* pA = (const float*)d_in[7];
  const float* pI = (const float*)d_in[8];
  const float* pL = (const float*)d_in[9];
  const float* eload = (const float*)d_in[10];
  const float* cw = (const float*)d_in[11];
  const float* cMc = (const float*)d_in[12];
  const int* conn = (const int*)d_in[13];
  const int* f_eid = (const int*)d_in[14];
  const int* f_isA = (const int*)d_in[15];

  const int N = in_sizes[1] / 3;  // F_ext is (N,3)
  const int E = in_sizes[6];      // prop_E is (E,)

  char* ws = (char*)d_ws;
  float* gacc = (float*)ws;
  size_t off = 256;
  float* ffA = (float*)(ws + off); off += (size_t)E * 3u * sizeof(float);
  float* ffB = (float*)(ws + off); off += (size_t)E * 3u * sizeof(float);
  float* dispc = nullptr;
  if (ws_size >= off + (size_t)N * 2u * sizeof(float)) {
    dispc = (float*)(ws + off); off += (size_t)N * 2u * sizeof(float);
  }

  hipMemsetAsync(gacc, 0, 256, stream);

  const int BLK = 256;
  const int maxNE = (N > E) ? N : E;
  const int nG = (maxNE + 3) >> 2;
  int grid = (nG + BLK - 1) / BLK;
  if (grid > 2048) grid = 2048;

  k_node<<<grid, BLK, 0, stream>>>(pred, F_ext, bc_disp, bc_rot, face_mask,
                                   f_eid, f_isA, ffA, ffB, dispc, gacc, N, E);
  k_elem1<<<grid, BLK, 0, stream>>>(pE, pA, pI, pL, eload, cw, cMc, gacc, E);
  k_pass2<<<grid, BLK, 0, stream>>>(conn, dirs, pE, pA, pL, cMc, ffA, ffB,
                                    dispc, pred, gacc, N, E);
  k_finish<<<1, 64, 0, stream>>>(gacc, (float*)d_out, (float)E);
}